// Round 12
// baseline (18102.928 us; speedup 1.0000x reference)
//
#include <hip/hip_runtime.h>
#include <stdint.h>

// ---------------------------------------------------------------------------
// RNN rollout. Phase 1: teacher-forced recurrence + bulk batched psi.
// Phase 2: persistent AR kernel, 8 groups x 32 members, member m -> XCD m%8
// (weights L2-resident). R12 = R11's validated primitives (batched relaxed
// agent-scope atomic-load staging, NO global_load_lds DMA — the DMA path is
// the replay-flake suspect: R8/R10 flaked, R11 4/4 clean) + R9's 4-barrier
// structure (exonerated by R10's flake of R8-verbatim): z lives in a
// block-local LDS parity dbuf; tail = stage h4 + L5 + FULL cell redundant
// per member -> z' never leaves the block; no barrier 5, no z exchange.
// Sizes fixed: B=128, T=256, HOR=512, OBS=32, LAT=256, HID=1024.
// ---------------------------------------------------------------------------

#define BATCH 128
#define TTF   256
#define HOR   512
#define OBS   32
#define LAT   256
#define HID   1024

#define GROUPS  8
#define MEMBERS 32
#define ARBLOCKS (GROUPS * MEMBERS)
#define ARTHREADS 128

typedef __attribute__((ext_vector_type(8))) short short8;
typedef __attribute__((ext_vector_type(4))) float floatx4;

// ---- workspace layout (bytes) — exchange buffers FIRST (R11 hardening) ----
#define OFF_HB    ((size_t)0)                          // 8 x 4 x 16x1024 bf16 (1 MB)
#define OFF_ZB    (OFF_HB + (size_t)GROUPS*4*16*HID*2) // (unused, layout compat)
#define OFF_CTR   (OFF_ZB + (size_t)GROUPS*2*16*LAT*2) // 8 x 128B counters
#define OFF_WB1   (OFF_CTR + (size_t)GROUPS*128)       // 1024x256 bf16 ([col][k])
#define OFF_WB2   (OFF_WB1 + (size_t)HID*LAT*2)        // 1024x1024 bf16
#define OFF_WB3   (OFF_WB2 + (size_t)HID*HID*2)
#define OFF_WB4   (OFF_WB3 + (size_t)HID*HID*2)
#define OFF_WB5   (OFF_WB4 + (size_t)HID*HID*2)        // 32x1024 bf16
#define OFF_CB    (OFF_WB5 + (size_t)OBS*HID*2)        // 256 f32 (b_ih+b_hh)
#define OFF_WHH2  (OFF_CB + (size_t)LAT*4)             // 64x256 uint2 packed W_hh^T
#define OFF_WIH2  (OFF_WHH2 + (size_t)64*256*8)        // 8x256 uint2 packed W_ih^T
#define OFF_ZF    (OFF_WIH2 + (size_t)8*256*8)         // 128x256 f32
#define OFF_Z     (OFF_ZF + (size_t)BATCH*LAT*4)       // 32768x256 bf16
#define OFF_WBC   (OFF_Z + (size_t)BATCH*TTF*LAT*2)    // 256x288 bf16 cell matrix
#define OFF_END   (OFF_WBC + (size_t)LAT*288*2)

__device__ __forceinline__ uint16_t f2bf(float f) {
    uint32_t u = __float_as_uint(f);
    u += 0x7fffu + ((u >> 16) & 1u);   // RNE
    return (uint16_t)(u >> 16);
}
__device__ __forceinline__ float bflo(uint32_t u) { return __uint_as_float(u << 16); }
__device__ __forceinline__ float bfhi(uint32_t u) { return __uint_as_float(u & 0xffff0000u); }

__device__ __forceinline__ float fast_tanh(float x) {
    float ax = fabsf(x);
    float e  = __expf(-2.f * ax);
    float r  = (1.f - e) / (1.f + e);
    return copysignf(r, x);
}

// XOR-granule swizzles (16B granule index ^ low bits of row). Producers store
// swizzled at MALL; the verbatim copy lands swizzled in LDS; readers XOR back.
__device__ __forceinline__ int hswz(int row, int col) {   // h: stride 1024
    return row * 1024 + ((((col >> 3) ^ (row & 7)) << 3) | (col & 7));
}
__device__ __forceinline__ int zswz(int row, int col) {   // z: stride 256
    return row * 256 + ((((col >> 3) ^ (row & 7)) << 3) | (col & 7));
}

// --- MALL-coherent primitives (relaxed agent atomics; 4/4 replay-validated) -
__device__ __forceinline__ void astore2(uint16_t* p, uint16_t v) {
    __hip_atomic_store(p, v, __ATOMIC_RELAXED, __HIP_MEMORY_SCOPE_AGENT);
}
__device__ __forceinline__ uint64_t aload8(const uint64_t* p) {
    return __hip_atomic_load(p, __ATOMIC_RELAXED, __HIP_MEMORY_SCOPE_AGENT);
}

// 32 KB h tile MALL -> LDS via batched atomic loads: two halves of 16
// independent 8B loads (all outstanding -> ~1 RTT each, overlapped), then
// LDS stores. No DMA instruction, no hand-coded cache bits.
__device__ __forceinline__ void stage_h(const uint16_t* src, uint16_t* dst, int tid) {
    const uint64_t* s = (const uint64_t*)((const char*)src + tid * 16);
    uint64_t* d = (uint64_t*)((char*)dst + tid * 16);
    #pragma unroll
    for (int half = 0; half < 2; half++) {
        uint64_t r[16];
        #pragma unroll
        for (int i = 0; i < 8; i++) {
            int j = half * 8 + i;
            r[2 * i]     = aload8(s + (size_t)j * 256);
            r[2 * i + 1] = aload8(s + (size_t)j * 256 + 1);
        }
        #pragma unroll
        for (int i = 0; i < 8; i++) {
            int j = half * 8 + i;
            d[(size_t)j * 256]     = r[2 * i];
            d[(size_t)j * 256 + 1] = r[2 * i + 1];
        }
    }
}

// group barrier, fence-free (validated R2/R3/R6/R11): __syncthreads drains
// vmcnt(0) (all MALL stores complete) before the flag add; flag is a MALL
// atomic; consumer loads bypass caches -> no buffer_inv -> weights stay
// L2-resident.
__device__ __forceinline__ void gbar(unsigned* ctr, unsigned target) {
    __syncthreads();
    if (threadIdx.x == 0) {
        __hip_atomic_fetch_add(ctr, 1u, __ATOMIC_RELAXED, __HIP_MEMORY_SCOPE_AGENT);
        while (__hip_atomic_load(ctr, __ATOMIC_RELAXED, __HIP_MEMORY_SCOPE_AGENT) < target) {}
    }
    __syncthreads();
}

// ---------------------------------------------------------------------------
// K0 helpers
// ---------------------------------------------------------------------------
__global__ void k_cvt(const float* __restrict__ s, uint16_t* __restrict__ d, int n) {
    int i = blockIdx.x * 256 + threadIdx.x;
    if (i < n) d[i] = f2bf(s[i]);
}

__global__ void k_cb(const float* __restrict__ a, const float* __restrict__ b,
                     float* __restrict__ c) {
    int j = threadIdx.x;
    c[j] = a[j] + b[j];
}

__global__ void k_pack(const float* __restrict__ w, uint2* __restrict__ dst, int klen) {
    int k4 = blockIdx.x, j = threadIdx.x;
    int k = k4 * 4;
    uint32_t a = f2bf(w[(size_t)j * klen + k + 0]);
    uint32_t b = f2bf(w[(size_t)j * klen + k + 1]);
    uint32_t c = f2bf(w[(size_t)j * klen + k + 2]);
    uint32_t d = f2bf(w[(size_t)j * klen + k + 3]);
    uint2 r; r.x = a | (b << 16); r.y = c | (d << 16);
    dst[k4 * 256 + j] = r;
}

__global__ void k_packc(const float* __restrict__ whh, const float* __restrict__ wih,
                        uint16_t* __restrict__ wbc) {
    int col = blockIdx.x;
    for (int k = threadIdx.x; k < 288; k += 256) {
        float v = (k < 256) ? whh[(size_t)col * 256 + k] : wih[(size_t)col * 32 + (k - 256)];
        wbc[(size_t)col * 288 + k] = f2bf(v);
    }
}

// ---------------------------------------------------------------------------
// K1: teacher-forced recurrence. 128 blocks x 256 threads.
// ---------------------------------------------------------------------------
__global__ __launch_bounds__(256) void k_rnn_tf(
    const float* __restrict__ y, const uint2* __restrict__ whh2,
    const uint2* __restrict__ wih2, const float* __restrict__ cb,
    uint16_t* __restrict__ Zg, float* __restrict__ zfinal)
{
    __shared__ alignas(16) float zl[LAT];
    __shared__ alignas(16) float ys[OBS];
    int j = threadIdx.x, b = blockIdx.x;
    zl[j] = 0.f;
    __syncthreads();
    const float4* z4 = (const float4*)zl;
    const float4* y4 = (const float4*)ys;
    for (int t = 0; t < TTF; t++) {
        if (j < OBS) ys[j] = y[(size_t)b * (TTF * OBS) + t * OBS + j];
        Zg[((size_t)b * TTF + t) * LAT + j] = f2bf(zl[j]);
        __syncthreads();
        float acc = cb[j];
        #pragma unroll 8
        for (int k4 = 0; k4 < 64; k4++) {
            uint2 wv = whh2[k4 * 256 + j];
            float4 zq = z4[k4];
            acc += bflo(wv.x) * zq.x + bfhi(wv.x) * zq.y
                 + bflo(wv.y) * zq.z + bfhi(wv.y) * zq.w;
        }
        #pragma unroll
        for (int k4 = 0; k4 < 8; k4++) {
            uint2 wv = wih2[k4 * 256 + j];
            float4 yq = y4[k4];
            acc += bflo(wv.x) * yq.x + bfhi(wv.x) * yq.y
                 + bflo(wv.y) * yq.z + bfhi(wv.y) * yq.w;
        }
        __syncthreads();
        zl[j] = fast_tanh(acc);
    }
    __syncthreads();
    zfinal[(size_t)b * LAT + j] = zl[j];
}

// ---------------------------------------------------------------------------
// K2: bulk psi over all 32768 phase-1 states. 1024 blocks x 32 rows, 512 thr.
// ---------------------------------------------------------------------------
__global__ __launch_bounds__(512) void k_psi_bulk(
    const uint16_t* __restrict__ Zg,
    const uint16_t* __restrict__ wb1, const uint16_t* __restrict__ wb2,
    const uint16_t* __restrict__ wb3, const uint16_t* __restrict__ wb4,
    const uint16_t* __restrict__ wb5,
    const float* __restrict__ b1, const float* __restrict__ b2,
    const float* __restrict__ b3, const float* __restrict__ b4,
    const float* __restrict__ b5, float* __restrict__ out)
{
    __shared__ uint16_t hbuf[32 * 1024];   // 64 KB, swizzled
    int tid = threadIdx.x;
    int w = tid >> 6, L = tid & 63, lm = L & 15, q = L >> 4;
    int rb = blockIdx.x * 32;
    int colbase = w * 128;
    floatx4 acc[2][8];
    const floatx4 zero = {0.f, 0.f, 0.f, 0.f};

    #pragma unroll
    for (int mt = 0; mt < 2; mt++)
        #pragma unroll
        for (int nt = 0; nt < 8; nt++) acc[mt][nt] = zero;
    for (int kc = 0; kc < 8; kc++) {
        short8 a0 = *(const short8*)(Zg + (size_t)(rb + lm) * LAT + kc * 32 + q * 8);
        short8 a1 = *(const short8*)(Zg + (size_t)(rb + 16 + lm) * LAT + kc * 32 + q * 8);
        #pragma unroll
        for (int nt = 0; nt < 8; nt++) {
            int n = colbase + nt * 16 + lm;
            short8 bf = *(const short8*)(wb1 + (size_t)n * LAT + kc * 32 + q * 8);
            acc[0][nt] = __builtin_amdgcn_mfma_f32_16x16x32_bf16(a0, bf, acc[0][nt], 0, 0, 0);
            acc[1][nt] = __builtin_amdgcn_mfma_f32_16x16x32_bf16(a1, bf, acc[1][nt], 0, 0, 0);
        }
    }
    #pragma unroll
    for (int mt = 0; mt < 2; mt++)
        #pragma unroll
        for (int nt = 0; nt < 8; nt++) {
            int col = colbase + nt * 16 + lm;
            float bias = b1[col];
            #pragma unroll
            for (int i = 0; i < 4; i++) {
                int row = mt * 16 + q * 4 + i;
                hbuf[hswz(row, col)] = f2bf(fmaxf(acc[mt][nt][i] + bias, 0.f));
            }
        }
    __syncthreads();

    const uint16_t* wbs[3] = {wb2, wb3, wb4};
    const float*    bbs[3] = {b2, b3, b4};
    for (int ll = 0; ll < 3; ll++) {
        const uint16_t* wb = wbs[ll];
        const float* bb = bbs[ll];
        #pragma unroll
        for (int mt = 0; mt < 2; mt++)
            #pragma unroll
            for (int nt = 0; nt < 8; nt++) acc[mt][nt] = zero;
        for (int kc = 0; kc < 32; kc++) {
            int g = ((kc * 4 + q) ^ (lm & 7)) << 3;
            short8 a0 = *(const short8*)(hbuf + lm * 1024 + g);
            short8 a1 = *(const short8*)(hbuf + (16 + lm) * 1024 + g);
            #pragma unroll
            for (int nt = 0; nt < 8; nt++) {
                int n = colbase + nt * 16 + lm;
                short8 bf = *(const short8*)(wb + (size_t)n * HID + kc * 32 + q * 8);
                acc[0][nt] = __builtin_amdgcn_mfma_f32_16x16x32_bf16(a0, bf, acc[0][nt], 0, 0, 0);
                acc[1][nt] = __builtin_amdgcn_mfma_f32_16x16x32_bf16(a1, bf, acc[1][nt], 0, 0, 0);
            }
        }
        __syncthreads();
        #pragma unroll
        for (int mt = 0; mt < 2; mt++)
            #pragma unroll
            for (int nt = 0; nt < 8; nt++) {
                int col = colbase + nt * 16 + lm;
                float bias = bb[col];
                #pragma unroll
                for (int i = 0; i < 4; i++) {
                    int row = mt * 16 + q * 4 + i;
                    hbuf[hswz(row, col)] = f2bf(fmaxf(acc[mt][nt][i] + bias, 0.f));
                }
            }
        __syncthreads();
    }

    if (w < 4) {
        int mt = w >> 1;
        int nb = (w & 1) * 16;
        floatx4 a5 = zero;
        for (int kc = 0; kc < 32; kc++) {
            int g = ((kc * 4 + q) ^ (lm & 7)) << 3;
            short8 a = *(const short8*)(hbuf + (mt * 16 + lm) * 1024 + g);
            short8 bf = *(const short8*)(wb5 + (size_t)(nb + lm) * HID + kc * 32 + q * 8);
            a5 = __builtin_amdgcn_mfma_f32_16x16x32_bf16(a, bf, a5, 0, 0, 0);
        }
        int col = nb + lm;
        float bias = b5[col];
        #pragma unroll
        for (int i = 0; i < 4; i++) {
            int row = mt * 16 + q * 4 + i;
            int r = rb + row;
            int bb_ = r >> 8, tt = r & 255;
            out[(size_t)bb_ * (HOR * OBS) + tt * OBS + col] = a5[i] + bias;
        }
    }
}

// ---------------------------------------------------------------------------
// K3 v12: persistent AR, 4 barriers/step. 8 groups x 32 members, 128 thr.
// Step: L1(LDS z) -> bar -> L2 -> bar -> L3 -> bar -> L4 -> bar ->
// [stage h4 -> L5 (all) -> full cell (redundant) -> z' in LDS] -> loop.
// All staging via batched atomic loads (no DMA). z never leaves the block.
// ---------------------------------------------------------------------------
__global__ __launch_bounds__(ARTHREADS) void k_ar2(
    const float* __restrict__ zfinal,
    const uint16_t* __restrict__ wb1, const uint16_t* __restrict__ wb2,
    const uint16_t* __restrict__ wb3, const uint16_t* __restrict__ wb4,
    const uint16_t* __restrict__ wb5, const uint16_t* __restrict__ wbc,
    const float* __restrict__ b1g, const float* __restrict__ b2g,
    const float* __restrict__ b3g, const float* __restrict__ b4g,
    const float* __restrict__ b5g, const float* __restrict__ cb,
    uint16_t* __restrict__ hb_all, uint16_t* __restrict__ zb_all,
    unsigned* __restrict__ ctr_all, float* __restrict__ out)
{
    (void)zb_all;   // z is LDS-only (signature kept = R11)
    __shared__ alignas(16) uint16_t hstg[16 * 1024];  // 32 KB staged h tile
    __shared__ alignas(16) uint16_t zls[2][16 * 256]; // 16 KB z parity dbuf
    __shared__ alignas(16) uint16_t yscr[16 * 32];    // 1 KB yh
    const int tid = threadIdx.x;
    const int g = blockIdx.x >> 5, m = blockIdx.x & 31;   // member m -> XCD m%8
    const int w = tid >> 6, L = tid & 63, lm = L & 15, q = L >> 4, lm7 = lm & 7;
    const int colbase = m * 32;
    const int cl = w * 16 + lm;
    const int rb = g * 16;
    uint16_t* hb = hb_all + (size_t)g * (4 * 16 * HID);
    unsigned* ctr = ctr_all + g * 32;
    const floatx4 zero = {0.f, 0.f, 0.f, 0.f};

    // bootstrap: z0 -> LDS parity 0 (swizzled), locally per block
    for (int idx = tid; idx < 16 * 256; idx += ARTHREADS) {
        int r = idx >> 8, c = idx & 255;
        zls[0][zswz(r, c)] = f2bf(zfinal[(size_t)(rb + r) * LAT + c]);
    }
    __syncthreads();
    unsigned tgt = 0;
    gbar(ctr, tgt += MEMBERS);   // align group start (counter init visible)

    uint16_t* h1 = hb;
    uint16_t* h2 = hb + 16 * HID;
    uint16_t* h3 = hb + 2 * 16 * HID;
    uint16_t* h4 = hb + 3 * 16 * HID;

    #pragma unroll 1
    for (int t = 0; t < HOR - TTF; t++) {
        const uint16_t* zc = zls[t & 1];
        uint16_t* zn = zls[(t + 1) & 1];

        // ---- L1: h1 slice from local z
        {
            floatx4 acc = zero;
            const uint16_t* bb = wb1 + (size_t)(colbase + cl) * LAT + q * 8;
            #pragma unroll
            for (int kc = 0; kc < 8; kc++) {
                int gz = (kc * 4 + q) ^ lm7;
                short8 a = *(const short8*)(zc + lm * 256 + gz * 8);
                short8 b = *(const short8*)(bb + kc * 32);
                acc = __builtin_amdgcn_mfma_f32_16x16x32_bf16(a, b, acc, 0, 0, 0);
            }
            int col = colbase + cl;
            float bias = b1g[col];
            #pragma unroll
            for (int i = 0; i < 4; i++)
                astore2(h1 + hswz(q * 4 + i, col), f2bf(fmaxf(acc[i] + bias, 0.f)));
        }
        gbar(ctr, tgt += MEMBERS);

        // ---- L2: stage h1 -> LDS, MFMA vs wb2 (L2-resident)
        stage_h(h1, hstg, tid);
        __syncthreads();
        {
            floatx4 acc = zero;
            const uint16_t* bb = wb2 + (size_t)(colbase + cl) * HID + q * 8;
            #pragma unroll 8
            for (int kc = 0; kc < 32; kc++) {
                int gh = (kc * 4 + q) ^ lm7;
                short8 a = *(const short8*)(hstg + lm * 1024 + gh * 8);
                short8 b = *(const short8*)(bb + kc * 32);
                acc = __builtin_amdgcn_mfma_f32_16x16x32_bf16(a, b, acc, 0, 0, 0);
            }
            int col = colbase + cl;
            float bias = b2g[col];
            #pragma unroll
            for (int i = 0; i < 4; i++)
                astore2(h2 + hswz(q * 4 + i, col), f2bf(fmaxf(acc[i] + bias, 0.f)));
        }
        gbar(ctr, tgt += MEMBERS);

        // ---- L3
        stage_h(h2, hstg, tid);
        __syncthreads();
        {
            floatx4 acc = zero;
            const uint16_t* bb = wb3 + (size_t)(colbase + cl) * HID + q * 8;
            #pragma unroll 8
            for (int kc = 0; kc < 32; kc++) {
                int gh = (kc * 4 + q) ^ lm7;
                short8 a = *(const short8*)(hstg + lm * 1024 + gh * 8);
                short8 b = *(const short8*)(bb + kc * 32);
                acc = __builtin_amdgcn_mfma_f32_16x16x32_bf16(a, b, acc, 0, 0, 0);
            }
            int col = colbase + cl;
            float bias = b3g[col];
            #pragma unroll
            for (int i = 0; i < 4; i++)
                astore2(h3 + hswz(q * 4 + i, col), f2bf(fmaxf(acc[i] + bias, 0.f)));
        }
        gbar(ctr, tgt += MEMBERS);

        // ---- L4
        stage_h(h3, hstg, tid);
        __syncthreads();
        {
            floatx4 acc = zero;
            const uint16_t* bb = wb4 + (size_t)(colbase + cl) * HID + q * 8;
            #pragma unroll 8
            for (int kc = 0; kc < 32; kc++) {
                int gh = (kc * 4 + q) ^ lm7;
                short8 a = *(const short8*)(hstg + lm * 1024 + gh * 8);
                short8 b = *(const short8*)(bb + kc * 32);
                acc = __builtin_amdgcn_mfma_f32_16x16x32_bf16(a, b, acc, 0, 0, 0);
            }
            int col = colbase + cl;
            float bias = b4g[col];
            #pragma unroll
            for (int i = 0; i < 4; i++)
                astore2(h4 + hswz(q * 4 + i, col), f2bf(fmaxf(acc[i] + bias, 0.f)));
        }
        gbar(ctr, tgt += MEMBERS);

        // ---- local tail (ALL members): stage h4 -> L5 -> full cell -> z'
        stage_h(h4, hstg, tid);
        __syncthreads();
        {
            // L5: wave w -> yh cols [16w,16w+16), redundant per member
            floatx4 a5 = zero;
            const uint16_t* bb = wb5 + (size_t)cl * HID + q * 8;
            #pragma unroll 8
            for (int kc = 0; kc < 32; kc++) {
                int gh = (kc * 4 + q) ^ lm7;
                short8 a = *(const short8*)(hstg + lm * 1024 + gh * 8);
                short8 b = *(const short8*)(bb + kc * 32);
                a5 = __builtin_amdgcn_mfma_f32_16x16x32_bf16(a, b, a5, 0, 0, 0);
            }
            float bias = b5g[cl];
            #pragma unroll
            for (int i = 0; i < 4; i++) {
                int row = q * 4 + i;
                float v = a5[i] + bias;
                yscr[row * 32 + cl] = f2bf(v);
                if (m == 0)
                    out[(size_t)(rb + row) * (HOR * OBS) + (TTF + t) * OBS + cl] = v;
            }
        }
        __syncthreads();   // yh visible block-wide
        {
            // full cell, redundant: wave w -> z' cols [128w,128w+128), K=288
            #pragma unroll
            for (int nt = 0; nt < 8; nt++) {
                int c = w * 128 + nt * 16 + lm;
                floatx4 cc = zero;
                const uint16_t* bbc = wbc + (size_t)c * 288 + q * 8;
                #pragma unroll
                for (int kc = 0; kc < 9; kc++) {
                    short8 a;
                    if (kc < 8) {
                        int gz = (kc * 4 + q) ^ lm7;
                        a = *(const short8*)(zc + lm * 256 + gz * 8);
                    } else {
                        a = *(const short8*)(yscr + lm * 32 + q * 8);
                    }
                    short8 b = *(const short8*)(bbc + kc * 32);
                    cc = __builtin_amdgcn_mfma_f32_16x16x32_bf16(a, b, cc, 0, 0, 0);
                }
                float cbv = cb[c];
                #pragma unroll
                for (int i = 0; i < 4; i++) {
                    int row = q * 4 + i;
                    zn[zswz(row, c)] = f2bf(fast_tanh(cc[i] + cbv));
                }
            }
        }
        __syncthreads();   // z' complete before next L1 reads it
    }
}

// ---------------------------------------------------------------------------
extern "C" void kernel_launch(void* const* d_in, const int* in_sizes, int n_in,
                              void* d_out, int out_size, void* d_ws, size_t ws_size,
                              hipStream_t stream) {
    (void)in_sizes; (void)n_in; (void)out_size; (void)ws_size;
    const float* y    = (const float*)d_in[0];
    const float* W_ih = (const float*)d_in[2];
    const float* W_hh = (const float*)d_in[3];
    const float* b_ih = (const float*)d_in[4];
    const float* b_hh = (const float*)d_in[5];
    const float* W1   = (const float*)d_in[6];
    const float* b1   = (const float*)d_in[7];
    const float* W2   = (const float*)d_in[8];
    const float* b2   = (const float*)d_in[9];
    const float* W3   = (const float*)d_in[10];
    const float* b3   = (const float*)d_in[11];
    const float* W4   = (const float*)d_in[12];
    const float* b4   = (const float*)d_in[13];
    const float* W5   = (const float*)d_in[14];
    const float* b5   = (const float*)d_in[15];
    float* out = (float*)d_out;
    char* ws = (char*)d_ws;

    uint16_t* HB   = (uint16_t*)(ws + OFF_HB);
    uint16_t* ZB   = (uint16_t*)(ws + OFF_ZB);
    unsigned* CTR  = (unsigned*)(ws + OFF_CTR);
    uint16_t* WB1  = (uint16_t*)(ws + OFF_WB1);
    uint16_t* WB2  = (uint16_t*)(ws + OFF_WB2);
    uint16_t* WB3  = (uint16_t*)(ws + OFF_WB3);
    uint16_t* WB4  = (uint16_t*)(ws + OFF_WB4);
    uint16_t* WB5  = (uint16_t*)(ws + OFF_WB5);
    float*    CB   = (float*)(ws + OFF_CB);
    uint2*    WHH2 = (uint2*)(ws + OFF_WHH2);
    uint2*    WIH2 = (uint2*)(ws + OFF_WIH2);
    float*    ZF   = (float*)(ws + OFF_ZF);
    uint16_t* Zbuf = (uint16_t*)(ws + OFF_Z);
    uint16_t* WBC  = (uint16_t*)(ws + OFF_WBC);

    // CTR memset FIRST: maximize traffic between this cached write and
    // k_ar2's MALL atomics (dirty-line eviction hazard — R11 hardening).
    hipMemsetAsync(CTR, 0, GROUPS * 128, stream);

    k_cvt<<<(HID*LAT + 255) / 256, 256, 0, stream>>>(W1, WB1, HID * LAT);
    k_cvt<<<(HID*HID + 255) / 256, 256, 0, stream>>>(W2, WB2, HID * HID);
    k_cvt<<<(HID*HID + 255) / 256, 256, 0, stream>>>(W3, WB3, HID * HID);
    k_cvt<<<(HID*HID + 255) / 256, 256, 0, stream>>>(W4, WB4, HID * HID);
    k_cvt<<<(OBS*HID + 255) / 256, 256, 0, stream>>>(W5, WB5, OBS * HID);
    k_cb<<<1, 256, 0, stream>>>(b_ih, b_hh, CB);
    k_pack<<<64, 256, 0, stream>>>(W_hh, WHH2, LAT);
    k_pack<<<8, 256, 0, stream>>>(W_ih, WIH2, OBS);
    k_packc<<<256, 256, 0, stream>>>(W_hh, W_ih, WBC);

    k_rnn_tf<<<BATCH, 256, 0, stream>>>(y, WHH2, WIH2, CB, Zbuf, ZF);

    k_psi_bulk<<<(BATCH * TTF) / 32, 512, 0, stream>>>(
        Zbuf, WB1, WB2, WB3, WB4, WB5, b1, b2, b3, b4, b5, out);

    // Cooperative launch preferred (guaranteed co-residency); on ANY error
    // fall back to a plain launch — 256 blocks at 1/CU on 256 CUs are
    // co-resident in practice.
    void* args[] = {
        (void*)&ZF, (void*)&WB1, (void*)&WB2, (void*)&WB3, (void*)&WB4,
        (void*)&WB5, (void*)&WBC, (void*)&b1, (void*)&b2, (void*)&b3,
        (void*)&b4, (void*)&b5, (void*)&CB, (void*)&HB, (void*)&ZB,
        (void*)&CTR, (void*)&out
    };
    hipError_t ce = hipLaunchCooperativeKernel((const void*)k_ar2,
                                               dim3(ARBLOCKS), dim3(ARTHREADS),
                                               args, 0, stream);
    if (ce != hipSuccess) {
        (void)hipGetLastError();   // clear sticky error
        k_ar2<<<dim3(ARBLOCKS), dim3(ARTHREADS), 0, stream>>>(
            ZF, WB1, WB2, WB3, WB4, WB5, WBC, b1, b2, b3, b4, b5, CB,
            HB, ZB, CTR, out);
    }
}

// Round 13
// 8335.236 us; speedup vs baseline: 2.1719x; 2.1719x over previous
//
#include <hip/hip_runtime.h>
#include <stdint.h>

// ---------------------------------------------------------------------------
// RNN rollout. Phase 1: teacher-forced recurrence + bulk batched psi.
// Phase 2: persistent AR kernel, 8 groups x 32 members, member m -> XCD m%8
// (weights L2-resident). R13 = R11 VERBATIM (best validated: 8.55 ms,
// first-call + graph-replay both pass).
// Session findings locked into this design:
//  - staging uses batched relaxed agent-scope atomic loads (4/4 replay-clean;
//    global_load_lds DMA with hand-coded aux flaked 2/3 -- do not reintroduce
//    without on-device race debugging);
//  - member m -> XCD m%8 keeps each XCD's weight slice ~1 MB (L2-resident;
//    group-per-XCD mapping thrashed 7 MB/XCD);
//  - cell computed as 32-col slices by members 0..7 only (R12's redundant
//    full-cell per block = 211 KB/member working set -> L2 thrash, 2.1x
//    regression);
//  - exchange buffers at workspace front + CTR memset first (poison
//    dirty-eviction hazard);
//  - cooperative launch return CHECKED with plain-launch fallback (silent
//    rejection cost 3 rounds).
// Sizes fixed: B=128, T=256, HOR=512, OBS=32, LAT=256, HID=1024.
// ---------------------------------------------------------------------------

#define BATCH 128
#define TTF   256
#define HOR   512
#define OBS   32
#define LAT   256
#define HID   1024

#define GROUPS  8
#define MEMBERS 32
#define ARBLOCKS (GROUPS * MEMBERS)
#define ARTHREADS 128

typedef __attribute__((ext_vector_type(8))) short short8;
typedef __attribute__((ext_vector_type(4))) float floatx4;

// ---- workspace layout (bytes) — exchange buffers FIRST ----
#define OFF_HB    ((size_t)0)                          // 8 x 4 x 16x1024 bf16 (1 MB)
#define OFF_ZB    (OFF_HB + (size_t)GROUPS*4*16*HID*2) // 8 x 2 x 16x256 bf16
#define OFF_CTR   (OFF_ZB + (size_t)GROUPS*2*16*LAT*2) // 8 x 128B counters
#define OFF_WB1   (OFF_CTR + (size_t)GROUPS*128)       // 1024x256 bf16 ([col][k])
#define OFF_WB2   (OFF_WB1 + (size_t)HID*LAT*2)        // 1024x1024 bf16
#define OFF_WB3   (OFF_WB2 + (size_t)HID*HID*2)
#define OFF_WB4   (OFF_WB3 + (size_t)HID*HID*2)
#define OFF_WB5   (OFF_WB4 + (size_t)HID*HID*2)        // 32x1024 bf16
#define OFF_CB    (OFF_WB5 + (size_t)OBS*HID*2)        // 256 f32 (b_ih+b_hh)
#define OFF_WHH2  (OFF_CB + (size_t)LAT*4)             // 64x256 uint2 packed W_hh^T
#define OFF_WIH2  (OFF_WHH2 + (size_t)64*256*8)        // 8x256 uint2 packed W_ih^T
#define OFF_ZF    (OFF_WIH2 + (size_t)8*256*8)         // 128x256 f32
#define OFF_Z     (OFF_ZF + (size_t)BATCH*LAT*4)       // 32768x256 bf16
#define OFF_WBC   (OFF_Z + (size_t)BATCH*TTF*LAT*2)    // 256x288 bf16 cell matrix
#define OFF_END   (OFF_WBC + (size_t)LAT*288*2)

__device__ __forceinline__ uint16_t f2bf(float f) {
    uint32_t u = __float_as_uint(f);
    u += 0x7fffu + ((u >> 16) & 1u);   // RNE
    return (uint16_t)(u >> 16);
}
__device__ __forceinline__ float bflo(uint32_t u) { return __uint_as_float(u << 16); }
__device__ __forceinline__ float bfhi(uint32_t u) { return __uint_as_float(u & 0xffff0000u); }

__device__ __forceinline__ float fast_tanh(float x) {
    float ax = fabsf(x);
    float e  = __expf(-2.f * ax);
    float r  = (1.f - e) / (1.f + e);
    return copysignf(r, x);
}

// XOR-granule swizzles (16B granule index ^ low bits of row). Producers store
// swizzled at MALL; the verbatim copy lands swizzled in LDS; readers XOR back.
__device__ __forceinline__ int hswz(int row, int col) {   // h: stride 1024
    return row * 1024 + ((((col >> 3) ^ (row & 7)) << 3) | (col & 7));
}
__device__ __forceinline__ int zswz(int row, int col) {   // z: stride 256
    return row * 256 + ((((col >> 3) ^ (row & 7)) << 3) | (col & 7));
}

// --- MALL-coherent primitives (relaxed agent atomics; replay-validated) ---
__device__ __forceinline__ void astore2(uint16_t* p, uint16_t v) {
    __hip_atomic_store(p, v, __ATOMIC_RELAXED, __HIP_MEMORY_SCOPE_AGENT);
}
__device__ __forceinline__ uint64_t aload8(const uint64_t* p) {
    return __hip_atomic_load(p, __ATOMIC_RELAXED, __HIP_MEMORY_SCOPE_AGENT);
}
__device__ __forceinline__ short8 aload16(const uint16_t* p) {
    union { short8 s; uint64_t u[2]; } v;
    v.u[0] = aload8((const uint64_t*)p);
    v.u[1] = aload8((const uint64_t*)p + 1);
    return v.s;
}

// 32 KB h tile MALL -> LDS via batched atomic loads: two halves of 16
// independent 8B loads (all outstanding -> ~1 RTT each, overlapped), then
// LDS stores. No DMA instruction, no hand-coded cache bits.
__device__ __forceinline__ void stage_h(const uint16_t* src, uint16_t* dst, int tid) {
    const uint64_t* s = (const uint64_t*)((const char*)src + tid * 16);
    uint64_t* d = (uint64_t*)((char*)dst + tid * 16);
    #pragma unroll
    for (int half = 0; half < 2; half++) {
        uint64_t r[16];
        #pragma unroll
        for (int i = 0; i < 8; i++) {
            int j = half * 8 + i;
            r[2 * i]     = aload8(s + (size_t)j * 256);
            r[2 * i + 1] = aload8(s + (size_t)j * 256 + 1);
        }
        #pragma unroll
        for (int i = 0; i < 8; i++) {
            int j = half * 8 + i;
            d[(size_t)j * 256]     = r[2 * i];
            d[(size_t)j * 256 + 1] = r[2 * i + 1];
        }
    }
}
// 8 KB z tile MALL -> LDS: one batch of 8 loads.
__device__ __forceinline__ void stage_z(const uint16_t* src, uint16_t* dst, int tid) {
    const uint64_t* s = (const uint64_t*)((const char*)src + tid * 16);
    uint64_t* d = (uint64_t*)((char*)dst + tid * 16);
    uint64_t r[8];
    #pragma unroll
    for (int j = 0; j < 4; j++) {
        r[2 * j]     = aload8(s + (size_t)j * 256);
        r[2 * j + 1] = aload8(s + (size_t)j * 256 + 1);
    }
    #pragma unroll
    for (int j = 0; j < 4; j++) {
        d[(size_t)j * 256]     = r[2 * j];
        d[(size_t)j * 256 + 1] = r[2 * j + 1];
    }
}

// group barrier, fence-free (validated R2/R3/R6/R11): __syncthreads drains
// vmcnt(0) (all MALL stores complete) before the flag add; flag is a MALL
// atomic; consumer loads bypass caches -> no buffer_inv -> weights stay
// L2-resident.
__device__ __forceinline__ void gbar(unsigned* ctr, unsigned target) {
    __syncthreads();
    if (threadIdx.x == 0) {
        __hip_atomic_fetch_add(ctr, 1u, __ATOMIC_RELAXED, __HIP_MEMORY_SCOPE_AGENT);
        while (__hip_atomic_load(ctr, __ATOMIC_RELAXED, __HIP_MEMORY_SCOPE_AGENT) < target) {}
    }
    __syncthreads();
}

// ---------------------------------------------------------------------------
// K0 helpers
// ---------------------------------------------------------------------------
__global__ void k_cvt(const float* __restrict__ s, uint16_t* __restrict__ d, int n) {
    int i = blockIdx.x * 256 + threadIdx.x;
    if (i < n) d[i] = f2bf(s[i]);
}

__global__ void k_cb(const float* __restrict__ a, const float* __restrict__ b,
                     float* __restrict__ c) {
    int j = threadIdx.x;
    c[j] = a[j] + b[j];
}

__global__ void k_pack(const float* __restrict__ w, uint2* __restrict__ dst, int klen) {
    int k4 = blockIdx.x, j = threadIdx.x;
    int k = k4 * 4;
    uint32_t a = f2bf(w[(size_t)j * klen + k + 0]);
    uint32_t b = f2bf(w[(size_t)j * klen + k + 1]);
    uint32_t c = f2bf(w[(size_t)j * klen + k + 2]);
    uint32_t d = f2bf(w[(size_t)j * klen + k + 3]);
    uint2 r; r.x = a | (b << 16); r.y = c | (d << 16);
    dst[k4 * 256 + j] = r;
}

__global__ void k_packc(const float* __restrict__ whh, const float* __restrict__ wih,
                        uint16_t* __restrict__ wbc) {
    int col = blockIdx.x;
    for (int k = threadIdx.x; k < 288; k += 256) {
        float v = (k < 256) ? whh[(size_t)col * 256 + k] : wih[(size_t)col * 32 + (k - 256)];
        wbc[(size_t)col * 288 + k] = f2bf(v);
    }
}

// ---------------------------------------------------------------------------
// K1: teacher-forced recurrence. 128 blocks x 256 threads.
// ---------------------------------------------------------------------------
__global__ __launch_bounds__(256) void k_rnn_tf(
    const float* __restrict__ y, const uint2* __restrict__ whh2,
    const uint2* __restrict__ wih2, const float* __restrict__ cb,
    uint16_t* __restrict__ Zg, float* __restrict__ zfinal)
{
    __shared__ alignas(16) float zl[LAT];
    __shared__ alignas(16) float ys[OBS];
    int j = threadIdx.x, b = blockIdx.x;
    zl[j] = 0.f;
    __syncthreads();
    const float4* z4 = (const float4*)zl;
    const float4* y4 = (const float4*)ys;
    for (int t = 0; t < TTF; t++) {
        if (j < OBS) ys[j] = y[(size_t)b * (TTF * OBS) + t * OBS + j];
        Zg[((size_t)b * TTF + t) * LAT + j] = f2bf(zl[j]);
        __syncthreads();
        float acc = cb[j];
        #pragma unroll 8
        for (int k4 = 0; k4 < 64; k4++) {
            uint2 wv = whh2[k4 * 256 + j];
            float4 zq = z4[k4];
            acc += bflo(wv.x) * zq.x + bfhi(wv.x) * zq.y
                 + bflo(wv.y) * zq.z + bfhi(wv.y) * zq.w;
        }
        #pragma unroll
        for (int k4 = 0; k4 < 8; k4++) {
            uint2 wv = wih2[k4 * 256 + j];
            float4 yq = y4[k4];
            acc += bflo(wv.x) * yq.x + bfhi(wv.x) * yq.y
                 + bflo(wv.y) * yq.z + bfhi(wv.y) * yq.w;
        }
        __syncthreads();
        zl[j] = fast_tanh(acc);
    }
    __syncthreads();
    zfinal[(size_t)b * LAT + j] = zl[j];
}

// ---------------------------------------------------------------------------
// K2: bulk psi over all 32768 phase-1 states. 1024 blocks x 32 rows, 512 thr.
// ---------------------------------------------------------------------------
__global__ __launch_bounds__(512) void k_psi_bulk(
    const uint16_t* __restrict__ Zg,
    const uint16_t* __restrict__ wb1, const uint16_t* __restrict__ wb2,
    const uint16_t* __restrict__ wb3, const uint16_t* __restrict__ wb4,
    const uint16_t* __restrict__ wb5,
    const float* __restrict__ b1, const float* __restrict__ b2,
    const float* __restrict__ b3, const float* __restrict__ b4,
    const float* __restrict__ b5, float* __restrict__ out)
{
    __shared__ uint16_t hbuf[32 * 1024];   // 64 KB, swizzled
    int tid = threadIdx.x;
    int w = tid >> 6, L = tid & 63, lm = L & 15, q = L >> 4;
    int rb = blockIdx.x * 32;
    int colbase = w * 128;
    floatx4 acc[2][8];
    const floatx4 zero = {0.f, 0.f, 0.f, 0.f};

    #pragma unroll
    for (int mt = 0; mt < 2; mt++)
        #pragma unroll
        for (int nt = 0; nt < 8; nt++) acc[mt][nt] = zero;
    for (int kc = 0; kc < 8; kc++) {
        short8 a0 = *(const short8*)(Zg + (size_t)(rb + lm) * LAT + kc * 32 + q * 8);
        short8 a1 = *(const short8*)(Zg + (size_t)(rb + 16 + lm) * LAT + kc * 32 + q * 8);
        #pragma unroll
        for (int nt = 0; nt < 8; nt++) {
            int n = colbase + nt * 16 + lm;
            short8 bf = *(const short8*)(wb1 + (size_t)n * LAT + kc * 32 + q * 8);
            acc[0][nt] = __builtin_amdgcn_mfma_f32_16x16x32_bf16(a0, bf, acc[0][nt], 0, 0, 0);
            acc[1][nt] = __builtin_amdgcn_mfma_f32_16x16x32_bf16(a1, bf, acc[1][nt], 0, 0, 0);
        }
    }
    #pragma unroll
    for (int mt = 0; mt < 2; mt++)
        #pragma unroll
        for (int nt = 0; nt < 8; nt++) {
            int col = colbase + nt * 16 + lm;
            float bias = b1[col];
            #pragma unroll
            for (int i = 0; i < 4; i++) {
                int row = mt * 16 + q * 4 + i;
                hbuf[hswz(row, col)] = f2bf(fmaxf(acc[mt][nt][i] + bias, 0.f));
            }
        }
    __syncthreads();

    const uint16_t* wbs[3] = {wb2, wb3, wb4};
    const float*    bbs[3] = {b2, b3, b4};
    for (int ll = 0; ll < 3; ll++) {
        const uint16_t* wb = wbs[ll];
        const float* bb = bbs[ll];
        #pragma unroll
        for (int mt = 0; mt < 2; mt++)
            #pragma unroll
            for (int nt = 0; nt < 8; nt++) acc[mt][nt] = zero;
        for (int kc = 0; kc < 32; kc++) {
            int g = ((kc * 4 + q) ^ (lm & 7)) << 3;
            short8 a0 = *(const short8*)(hbuf + lm * 1024 + g);
            short8 a1 = *(const short8*)(hbuf + (16 + lm) * 1024 + g);
            #pragma unroll
            for (int nt = 0; nt < 8; nt++) {
                int n = colbase + nt * 16 + lm;
                short8 bf = *(const short8*)(wb + (size_t)n * HID + kc * 32 + q * 8);
                acc[0][nt] = __builtin_amdgcn_mfma_f32_16x16x32_bf16(a0, bf, acc[0][nt], 0, 0, 0);
                acc[1][nt] = __builtin_amdgcn_mfma_f32_16x16x32_bf16(a1, bf, acc[1][nt], 0, 0, 0);
            }
        }
        __syncthreads();
        #pragma unroll
        for (int mt = 0; mt < 2; mt++)
            #pragma unroll
            for (int nt = 0; nt < 8; nt++) {
                int col = colbase + nt * 16 + lm;
                float bias = bb[col];
                #pragma unroll
                for (int i = 0; i < 4; i++) {
                    int row = mt * 16 + q * 4 + i;
                    hbuf[hswz(row, col)] = f2bf(fmaxf(acc[mt][nt][i] + bias, 0.f));
                }
            }
        __syncthreads();
    }

    if (w < 4) {
        int mt = w >> 1;
        int nb = (w & 1) * 16;
        floatx4 a5 = zero;
        for (int kc = 0; kc < 32; kc++) {
            int g = ((kc * 4 + q) ^ (lm & 7)) << 3;
            short8 a = *(const short8*)(hbuf + (mt * 16 + lm) * 1024 + g);
            short8 bf = *(const short8*)(wb5 + (size_t)(nb + lm) * HID + kc * 32 + q * 8);
            a5 = __builtin_amdgcn_mfma_f32_16x16x32_bf16(a, bf, a5, 0, 0, 0);
        }
        int col = nb + lm;
        float bias = b5[col];
        #pragma unroll
        for (int i = 0; i < 4; i++) {
            int row = mt * 16 + q * 4 + i;
            int r = rb + row;
            int bb_ = r >> 8, tt = r & 255;
            out[(size_t)bb_ * (HOR * OBS) + tt * OBS + col] = a5[i] + bias;
        }
    }
}

// ---------------------------------------------------------------------------
// K3 v11 (R13 = R11 verbatim): persistent AR. 8 groups x 32 members, 128 thr.
// Per step: stage z tile -> LDS (batched atomic loads); L1 from LDS; per
// h-stage: gbar -> stage h tile -> MFMA vs L2-resident weights; stage5
// (m<8): L5 + cell slice, z' -> MALL.
// ---------------------------------------------------------------------------
__global__ __launch_bounds__(ARTHREADS) void k_ar2(
    const float* __restrict__ zfinal,
    const uint16_t* __restrict__ wb1, const uint16_t* __restrict__ wb2,
    const uint16_t* __restrict__ wb3, const uint16_t* __restrict__ wb4,
    const uint16_t* __restrict__ wb5, const uint16_t* __restrict__ wbc,
    const float* __restrict__ b1g, const float* __restrict__ b2g,
    const float* __restrict__ b3g, const float* __restrict__ b4g,
    const float* __restrict__ b5g, const float* __restrict__ cb,
    uint16_t* __restrict__ hb_all, uint16_t* __restrict__ zb_all,
    unsigned* __restrict__ ctr_all, float* __restrict__ out)
{
    __shared__ alignas(16) uint16_t hstg[16 * 1024];  // 32 KB staged h tile
    __shared__ alignas(16) uint16_t zstg[16 * 256];   // 8 KB staged z tile
    __shared__ alignas(16) uint16_t yscr[16 * 32];    // 1 KB
    const int tid = threadIdx.x;
    const int g = blockIdx.x >> 5, m = blockIdx.x & 31;   // member m -> XCD m%8
    const int w = tid >> 6, L = tid & 63, lm = L & 15, q = L >> 4, lm7 = lm & 7;
    const int colbase = m * 32;
    const int cl = w * 16 + lm;
    const int rb = g * 16;
    uint16_t* hb = hb_all + (size_t)g * (4 * 16 * HID);
    uint16_t* zb = zb_all + (size_t)g * (2 * 16 * LAT);
    unsigned* ctr = ctr_all + g * 32;
    const floatx4 zero = {0.f, 0.f, 0.f, 0.f};

    // member 0: zfinal -> z parity 0 at MALL, pre-swizzled
    if (m == 0) {
        for (int idx = tid; idx < 16 * 256; idx += ARTHREADS) {
            int r = idx >> 8, c = idx & 255;
            astore2(zb + zswz(r, c), f2bf(zfinal[(size_t)(rb + r) * LAT + c]));
        }
    }
    unsigned tgt = 0;
    gbar(ctr, tgt += MEMBERS);

    uint16_t* h1 = hb;
    uint16_t* h2 = hb + 16 * HID;
    uint16_t* h3 = hb + 2 * 16 * HID;
    uint16_t* h4 = hb + 3 * 16 * HID;

    #pragma unroll 1
    for (int t = 0; t < HOR - TTF; t++) {
        uint16_t* zcur = zb + (t & 1) * (16 * 256);
        uint16_t* znext = zb + ((t + 1) & 1) * (16 * 256);

        // ---- stage z tile into LDS, then L1 from LDS
        stage_z(zcur, zstg, tid);
        __syncthreads();
        {
            floatx4 acc = zero;
            const uint16_t* bb = wb1 + (size_t)(colbase + cl) * LAT + q * 8;
            #pragma unroll
            for (int kc = 0; kc < 8; kc++) {
                int gz = (kc * 4 + q) ^ lm7;
                short8 a = *(const short8*)(zstg + lm * 256 + gz * 8);
                short8 b = *(const short8*)(bb + kc * 32);
                acc = __builtin_amdgcn_mfma_f32_16x16x32_bf16(a, b, acc, 0, 0, 0);
            }
            int col = colbase + cl;
            float bias = b1g[col];
            #pragma unroll
            for (int i = 0; i < 4; i++)
                astore2(h1 + hswz(q * 4 + i, col), f2bf(fmaxf(acc[i] + bias, 0.f)));
        }
        gbar(ctr, tgt += MEMBERS);

        // ---- L2: stage h1 -> LDS, MFMA vs wb2 (L2-resident)
        stage_h(h1, hstg, tid);
        __syncthreads();
        {
            floatx4 acc = zero;
            const uint16_t* bb = wb2 + (size_t)(colbase + cl) * HID + q * 8;
            #pragma unroll 8
            for (int kc = 0; kc < 32; kc++) {
                int gh = (kc * 4 + q) ^ lm7;
                short8 a = *(const short8*)(hstg + lm * 1024 + gh * 8);
                short8 b = *(const short8*)(bb + kc * 32);
                acc = __builtin_amdgcn_mfma_f32_16x16x32_bf16(a, b, acc, 0, 0, 0);
            }
            int col = colbase + cl;
            float bias = b2g[col];
            #pragma unroll
            for (int i = 0; i < 4; i++)
                astore2(h2 + hswz(q * 4 + i, col), f2bf(fmaxf(acc[i] + bias, 0.f)));
        }
        gbar(ctr, tgt += MEMBERS);

        // ---- L3
        stage_h(h2, hstg, tid);
        __syncthreads();
        {
            floatx4 acc = zero;
            const uint16_t* bb = wb3 + (size_t)(colbase + cl) * HID + q * 8;
            #pragma unroll 8
            for (int kc = 0; kc < 32; kc++) {
                int gh = (kc * 4 + q) ^ lm7;
                short8 a = *(const short8*)(hstg + lm * 1024 + gh * 8);
                short8 b = *(const short8*)(bb + kc * 32);
                acc = __builtin_amdgcn_mfma_f32_16x16x32_bf16(a, b, acc, 0, 0, 0);
            }
            int col = colbase + cl;
            float bias = b3g[col];
            #pragma unroll
            for (int i = 0; i < 4; i++)
                astore2(h3 + hswz(q * 4 + i, col), f2bf(fmaxf(acc[i] + bias, 0.f)));
        }
        gbar(ctr, tgt += MEMBERS);

        // ---- L4
        stage_h(h3, hstg, tid);
        __syncthreads();
        {
            floatx4 acc = zero;
            const uint16_t* bb = wb4 + (size_t)(colbase + cl) * HID + q * 8;
            #pragma unroll 8
            for (int kc = 0; kc < 32; kc++) {
                int gh = (kc * 4 + q) ^ lm7;
                short8 a = *(const short8*)(hstg + lm * 1024 + gh * 8);
                short8 b = *(const short8*)(bb + kc * 32);
                acc = __builtin_amdgcn_mfma_f32_16x16x32_bf16(a, b, acc, 0, 0, 0);
            }
            int col = colbase + cl;
            float bias = b4g[col];
            #pragma unroll
            for (int i = 0; i < 4; i++)
                astore2(h4 + hswz(q * 4 + i, col), f2bf(fmaxf(acc[i] + bias, 0.f)));
        }
        gbar(ctr, tgt += MEMBERS);

        // ---- stage 5 (members 0..7): stage h4, L5 redundant + cell slice
        if (m < 8) {
            stage_h(h4, hstg, tid);
            __syncthreads();
            floatx4 a5 = zero;
            const uint16_t* bb = wb5 + (size_t)cl * HID + q * 8;
            #pragma unroll 8
            for (int kc = 0; kc < 32; kc++) {
                int gh = (kc * 4 + q) ^ lm7;
                short8 a = *(const short8*)(hstg + lm * 1024 + gh * 8);
                short8 b = *(const short8*)(bb + kc * 32);
                a5 = __builtin_amdgcn_mfma_f32_16x16x32_bf16(a, b, a5, 0, 0, 0);
            }
            float bias = b5g[cl];
            float vout[4];
            #pragma unroll
            for (int i = 0; i < 4; i++) {
                float v = a5[i] + bias;
                vout[i] = v;
                yscr[(q * 4 + i) * 32 + cl] = f2bf(v);
            }
            if (m == 0) {
                #pragma unroll
                for (int i = 0; i < 4; i++)
                    out[(size_t)(rb + q * 4 + i) * (HOR * OBS) + (TTF + t) * OBS + cl] = vout[i];
            }
            __syncthreads();
            // cell: z' cols [32m,32m+32), A = [z(LDS) | yh(LDS)], K=288
            floatx4 cc = zero;
            int ccol = m * 32 + cl;
            const uint16_t* bb2 = wbc + (size_t)ccol * 288 + q * 8;
            #pragma unroll
            for (int kc = 0; kc < 9; kc++) {
                short8 a;
                if (kc < 8) {
                    int gz = (kc * 4 + q) ^ lm7;
                    a = *(const short8*)(zstg + lm * 256 + gz * 8);
                } else {
                    a = *(const short8*)(yscr + lm * 32 + q * 8);
                }
                short8 b = *(const short8*)(bb2 + kc * 32);
                cc = __builtin_amdgcn_mfma_f32_16x16x32_bf16(a, b, cc, 0, 0, 0);
            }
            float cbv = cb[ccol];
            #pragma unroll
            for (int i = 0; i < 4; i++)
                astore2(znext + zswz(q * 4 + i, ccol), f2bf(fast_tanh(cc[i] + cbv)));
        }
        gbar(ctr, tgt += MEMBERS);
    }
}

// ---------------------------------------------------------------------------
extern "C" void kernel_launch(void* const* d_in, const int* in_sizes, int n_in,
                              void* d_out, int out_size, void* d_ws, size_t ws_size,
                              hipStream_t stream) {
    (void)in_sizes; (void)n_in; (void)out_size; (void)ws_size;
    const float* y    = (const float*)d_in[0];
    const float* W_ih = (const float*)d_in[2];
    const float* W_hh = (const float*)d_in[3];
    const float* b_ih = (const float*)d_in[4];
    const float* b_hh = (const float*)d_in[5];
    const float* W1   = (const float*)d_in[6];
    const float* b1   = (const float*)d_in[7];
    const float* W2   = (const float*)d_in[8];
    const float* b2   = (const float*)d_in[9];
    const float* W3   = (const float*)d_in[10];
    const float* b3   = (const float*)d_in[11];
    const float* W4   = (const float*)d_in[12];
    const float* b4   = (const float*)d_in[13];
    const float* W5   = (const float*)d_in[14];
    const float* b5   = (const float*)d_in[15];
    float* out = (float*)d_out;
    char* ws = (char*)d_ws;

    uint16_t* HB   = (uint16_t*)(ws + OFF_HB);
    uint16_t* ZB   = (uint16_t*)(ws + OFF_ZB);
    unsigned* CTR  = (unsigned*)(ws + OFF_CTR);
    uint16_t* WB1  = (uint16_t*)(ws + OFF_WB1);
    uint16_t* WB2  = (uint16_t*)(ws + OFF_WB2);
    uint16_t* WB3  = (uint16_t*)(ws + OFF_WB3);
    uint16_t* WB4  = (uint16_t*)(ws + OFF_WB4);
    uint16_t* WB5  = (uint16_t*)(ws + OFF_WB5);
    float*    CB   = (float*)(ws + OFF_CB);
    uint2*    WHH2 = (uint2*)(ws + OFF_WHH2);
    uint2*    WIH2 = (uint2*)(ws + OFF_WIH2);
    float*    ZF   = (float*)(ws + OFF_ZF);
    uint16_t* Zbuf = (uint16_t*)(ws + OFF_Z);
    uint16_t* WBC  = (uint16_t*)(ws + OFF_WBC);

    // CTR memset FIRST: maximize traffic between this cached write and
    // k_ar2's MALL atomics (dirty-line eviction hazard — R11 hardening).
    hipMemsetAsync(CTR, 0, GROUPS * 128, stream);

    k_cvt<<<(HID*LAT + 255) / 256, 256, 0, stream>>>(W1, WB1, HID * LAT);
    k_cvt<<<(HID*HID + 255) / 256, 256, 0, stream>>>(W2, WB2, HID * HID);
    k_cvt<<<(HID*HID + 255) / 256, 256, 0, stream>>>(W3, WB3, HID * HID);
    k_cvt<<<(HID*HID + 255) / 256, 256, 0, stream>>>(W4, WB4, HID * HID);
    k_cvt<<<(OBS*HID + 255) / 256, 256, 0, stream>>>(W5, WB5, OBS * HID);
    k_cb<<<1, 256, 0, stream>>>(b_ih, b_hh, CB);
    k_pack<<<64, 256, 0, stream>>>(W_hh, WHH2, LAT);
    k_pack<<<8, 256, 0, stream>>>(W_ih, WIH2, OBS);
    k_packc<<<256, 256, 0, stream>>>(W_hh, W_ih, WBC);

    k_rnn_tf<<<BATCH, 256, 0, stream>>>(y, WHH2, WIH2, CB, Zbuf, ZF);

    k_psi_bulk<<<(BATCH * TTF) / 32, 512, 0, stream>>>(
        Zbuf, WB1, WB2, WB3, WB4, WB5, b1, b2, b3, b4, b5, out);

    // Cooperative launch preferred (guaranteed co-residency); on ANY error
    // fall back to a plain launch — 256 blocks at 1/CU on 256 CUs are
    // co-resident in practice.
    void* args[] = {
        (void*)&ZF, (void*)&WB1, (void*)&WB2, (void*)&WB3, (void*)&WB4,
        (void*)&WB5, (void*)&WBC, (void*)&b1, (void*)&b2, (void*)&b3,
        (void*)&b4, (void*)&b5, (void*)&CB, (void*)&HB, (void*)&ZB,
        (void*)&CTR, (void*)&out
    };
    hipError_t ce = hipLaunchCooperativeKernel((const void*)k_ar2,
                                               dim3(ARBLOCKS), dim3(ARTHREADS),
                                               args, 0, stream);
    if (ce != hipSuccess) {
        (void)hipGetLastError();   // clear sticky error
        k_ar2<<<dim3(ARBLOCKS), dim3(ARTHREADS), 0, stream>>>(
            ZF, WB1, WB2, WB3, WB4, WB5, WBC, b1, b2, b3, b4, b5, CB,
            HB, ZB, CTR, out);
    }
}